// Round 4
// baseline (152.114 us; speedup 1.0000x reference)
//
#include <hip/hip_runtime.h>

#define TSEQ 512
#define CDIM 512
#define NH 8
#define HS 64
#define BBATCH 32
#define MROWS (BBATCH * TSEQ)   // 16384

#define BM 128
#define BN 128
#define BK 32

typedef unsigned short u16;
typedef __bf16 bf16x8 __attribute__((ext_vector_type(8)));
typedef float f32x4 __attribute__((ext_vector_type(4)));
typedef float f32x16 __attribute__((ext_vector_type(16)));

// round-to-nearest-even fp32 -> bf16 bits
__device__ __forceinline__ u16 f2b(float f) {
  union { float f; unsigned u; } v; v.f = f;
  unsigned r = (v.u + 0x7fffu + ((v.u >> 16) & 1u)) >> 16;
  return (u16)r;
}

__device__ __forceinline__ void gload_lds16(const u16* g, u16* l) {
  __builtin_amdgcn_global_load_lds(
      (const __attribute__((address_space(1))) void*)g,
      (__attribute__((address_space(3))) void*)l, 16, 0, 0);
}

// ---------------- prep kernels ----------------

__global__ __launch_bounds__(256) void conv_x(const float* __restrict__ x,
                                              u16* __restrict__ xb) {
  int i = blockIdx.x * 256 + threadIdx.x;       // MROWS*CDIM/4 elements
  float4 v = reinterpret_cast<const float4*>(x)[i];
  ushort4 o;
  o.x = f2b(v.x); o.y = f2b(v.y); o.z = f2b(v.z); o.w = f2b(v.w);
  reinterpret_cast<ushort4*>(xb)[i] = o;
}

// transpose Wq,Wk,Wv -> wtA[1536][512] bf16 ; Wo -> woT[512][512] bf16
__global__ __launch_bounds__(256) void transpose_w(const float* __restrict__ wq,
                                                   const float* __restrict__ wk,
                                                   const float* __restrict__ wv,
                                                   const float* __restrict__ wo,
                                                   u16* __restrict__ wtA,
                                                   u16* __restrict__ woT) {
  __shared__ float tile[32][33];
  int mat = blockIdx.z;
  const float* src = (mat == 0) ? wq : (mat == 1) ? wk : (mat == 2) ? wv : wo;
  u16* dst = (mat < 3) ? (wtA + (size_t)mat * CDIM * CDIM) : woT;
  int kb = blockIdx.x * 32, nb = blockIdx.y * 32;
  int tx = threadIdx.x, ty = threadIdx.y;
#pragma unroll
  for (int rr = 0; rr < 32; rr += 8)
    tile[ty + rr][tx] = src[(size_t)(kb + ty + rr) * CDIM + nb + tx];
  __syncthreads();
#pragma unroll
  for (int rr = 0; rr < 32; rr += 8)
    dst[(size_t)(nb + ty + rr) * CDIM + kb + tx] = f2b(tile[tx][ty + rr]);
}

__global__ __launch_bounds__(256) void rope_tab(float* __restrict__ cosT,
                                                float* __restrict__ sinT) {
  int i = blockIdx.x * 256 + threadIdx.x;       // 512*32
  int t = i >> 5, f = i & 31;
  float inv = __powf(10000.0f, -(float)f / 32.0f);
  float ang = (float)t * inv;
  cosT[i] = cosf(ang);
  sinT[i] = sinf(ang);
}

// ---------------- fused QKV GEMM + RoPE (m97 structure) ----------------
__global__ __launch_bounds__(256) void qkv_gemm(const u16* __restrict__ xb,
                                                const u16* __restrict__ wtA,
                                                const float* __restrict__ cosT,
                                                const float* __restrict__ sinT,
                                                u16* __restrict__ Qb,
                                                u16* __restrict__ Kb,
                                                u16* __restrict__ VT) {
  __shared__ __align__(16) u16 smem[BM * BK + BN * BK];   // 16 KB
  u16* lsA = smem;
  u16* lsB = smem + BM * BK;
  const int tid = threadIdx.x;
  const int lane = tid & 63;
  const int l16 = lane & 15, lg = lane >> 4;
  const int wid = tid >> 6;
  const int wr = wid >> 1, wc = wid & 1;
  const int m0 = blockIdx.x * BM;
  const int n0 = blockIdx.y * BN;

  const u16* gA = xb + (size_t)m0 * CDIM;
  const u16* gB = wtA + (size_t)n0 * CDIM;

  f32x4 acc[4][4] = {};

  for (int kt = 0; kt < CDIM; kt += BK) {
#pragma unroll
    for (int c = 0; c < 2; ++c) {
      int flat = c * 2048 + tid * 8;           // element index in 128x32 tile
      int row = flat >> 5, col = flat & 31;
      gload_lds16(gA + (size_t)row * CDIM + kt + col, lsA + flat);
      gload_lds16(gB + (size_t)row * CDIM + kt + col, lsB + flat);
    }
    __syncthreads();
    bf16x8 af[4], bfr[4];
#pragma unroll
    for (int m = 0; m < 4; ++m)
      af[m] = *reinterpret_cast<const bf16x8*>(lsA + (wr * 64 + m * 16 + l16) * BK + lg * 8);
#pragma unroll
    for (int n = 0; n < 4; ++n)
      bfr[n] = *reinterpret_cast<const bf16x8*>(lsB + (wc * 64 + n * 16 + l16) * BK + lg * 8);
#pragma unroll
    for (int m = 0; m < 4; ++m)
#pragma unroll
      for (int n = 0; n < 4; ++n)
        acc[m][n] = __builtin_amdgcn_mfma_f32_16x16x32_bf16(af[m], bfr[n], acc[m][n], 0, 0, 0);
    __syncthreads();
  }

  // ---- epilogue: RoPE for Q/K, LDS-transposed coalesced store for V ----
  const int gcolbase = n0 + wc * 64;
  const int mat = gcolbase >> 9;               // 0:Q 1:K 2:V (block-uniform)
  const int bidx = m0 >> 9;
  if (mat < 2) {
    u16* dst = (mat == 0) ? Qb : Kb;
#pragma unroll
    for (int n = 0; n < 4; ++n) {
      int gcol = gcolbase + n * 16 + l16;
      int nc = gcol & 511;
      int dd = nc & 63;
      int fi = dd >> 1;
#pragma unroll
      for (int m = 0; m < 4; ++m)
#pragma unroll
        for (int r = 0; r < 4; ++r) {
          int row = m0 + wr * 64 + m * 16 + lg * 4 + r;
          int t = row & (TSEQ - 1);
          float v = acc[m][n][r];
          float o = __shfl_xor(v, 1);          // RoPE partner column
          float c = cosT[t * 32 + fi];
          float sn = sinT[t * 32 + fi];
          float res = (dd & 1) ? (v * c + o * sn) : (v * c - o * sn);
          dst[(size_t)row * CDIM + nc] = f2b(res);
        }
    }
  } else {
    // V: transpose 128t x 128col block through LDS (reuse staging smem),
    // store VT rows as coalesced 16B chunks. Two passes of 64 t each.
    const int head_base = (n0 & 511) >> 6;
    char* vld = reinterpret_cast<char*>(smem);   // [128 col][64 t] u16, XOR-swizzled
#pragma unroll
    for (int hpass = 0; hpass < 2; ++hpass) {
      if (wr == hpass) {
#pragma unroll
        for (int n = 0; n < 4; ++n) {
          int c = wc * 64 + n * 16 + l16;
#pragma unroll
          for (int m = 0; m < 4; ++m) {
            int tl = m * 16 + lg * 4;
            ushort4 pk;
            pk.x = f2b(acc[m][n][0]); pk.y = f2b(acc[m][n][1]);
            pk.z = f2b(acc[m][n][2]); pk.w = f2b(acc[m][n][3]);
            unsigned bo = (unsigned)(c * 128 + tl * 2) ^ ((unsigned)(c & 7) << 4);
            *reinterpret_cast<ushort4*>(vld + bo) = pk;
          }
        }
      }
      __syncthreads();
      {
        int c = tid >> 1;
        int hh_g = head_base + (c >> 6);
        int dd = c & 63;
        size_t rowbase = (size_t)((bidx * NH + hh_g) * HS + dd) * TSEQ
                         + (m0 & (TSEQ - 1)) + hpass * 64;
#pragma unroll
        for (int i = 0; i < 4; ++i) {
          int chunk = (tid & 1) * 4 + i;
          unsigned bo = (unsigned)(c * 128 + chunk * 16) ^ ((unsigned)(c & 7) << 4);
          int4 vdat = *reinterpret_cast<const int4*>(vld + bo);
          *reinterpret_cast<int4*>(VT + rowbase + chunk * 8) = vdat;
        }
      }
      __syncthreads();
    }
  }
}

// ---------------- flash attention (swapped QK^T, 32x32 MFMA, no LDS) -------
// grid (B*H, TSEQ/128), block 256 (4 waves). Each wave: 32 q-rows, lane owns
// ONE q-column (q = q0 + (lane&31)); softmax is lane-local.
__global__ __launch_bounds__(256, 4) void attn_kern(const u16* __restrict__ Qb,
                                                    const u16* __restrict__ Kb,
                                                    const u16* __restrict__ VT,
                                                    u16* __restrict__ att) {
  const int lane = threadIdx.x & 63, wid = threadIdx.x >> 6;
  const int l31 = lane & 31, hh = lane >> 5;
  const int bh = blockIdx.x, b = bh >> 3, h = bh & 7;
  const int q0 = blockIdx.y * 128 + wid * 32;

  bf16x8 qf[4];
  const u16* qbase = Qb + (size_t)(b * TSEQ + q0 + l31) * CDIM + h * HS + hh * 8;
#pragma unroll
  for (int ds = 0; ds < 4; ++ds)
    qf[ds] = *reinterpret_cast<const bf16x8*>(qbase + ds * 16);

  const float SC = 0.125f * 1.4426950408889634f;  // scale * log2(e)
  float m_r = -1e30f, lsum = 0.0f;
  f32x16 of[2] = {};   // O^T[d][q]: of[dt], d = dt*32 + (r&3)+8*(r>>2)+4*hh

  const int nkt = (q0 >> 5) + 1;
  for (int kt = 0; kt < nkt; ++kt) {
    // S^T[k][q] = mfma(K as A, Q as B)
    f32x16 s = {};
    const u16* kr = Kb + (size_t)(b * TSEQ + kt * 32 + l31) * CDIM + h * HS + hh * 8;
#pragma unroll
    for (int ds = 0; ds < 4; ++ds) {
      bf16x8 kf = *reinterpret_cast<const bf16x8*>(kr + ds * 16);
      s = __builtin_amdgcn_mfma_f32_32x32x16_bf16(kf, qf[ds], s, 0, 0, 0);
    }
    float p[16];
#pragma unroll
    for (int r = 0; r < 16; ++r) p[r] = s[r] * SC;
    if (kt == nkt - 1) {          // diagonal tile: mask k > q
#pragma unroll
      for (int r = 0; r < 16; ++r) {
        int kk = (r & 3) + 8 * (r >> 2) + 4 * hh;
        if (kk > l31) p[r] = -1e30f;
      }
    }
    float pm = p[0];
#pragma unroll
    for (int r = 1; r < 16; ++r) pm = fmaxf(pm, p[r]);
    pm = fmaxf(pm, __shfl_xor(pm, 32));
    if (!__all(pm - m_r <= 8.0f)) {   // T13 defer-max
      float mn = fmaxf(m_r, pm);
      float alpha = exp2f(m_r - mn);
      m_r = mn;
      lsum *= alpha;
#pragma unroll
      for (int r = 0; r < 16; ++r) { of[0][r] *= alpha; of[1][r] *= alpha; }
    }
    float ts = 0.0f;
#pragma unroll
    for (int r = 0; r < 16; ++r) { p[r] = exp2f(p[r] - m_r); ts += p[r]; }
    ts += __shfl_xor(ts, 32);
    lsum += ts;

    // P^T -> bf16 B-fragments via cvt_pk + permlane32_swap (T12)
    unsigned w0, w1, w2, w3, w4, w5, w6, w7;
    asm("v_cvt_pk_bf16_f32 %0, %1, %2" : "=v"(w0) : "v"(p[0]),  "v"(p[1]));
    asm("v_cvt_pk_bf16_f32 %0, %1, %2" : "=v"(w1) : "v"(p[2]),  "v"(p[3]));
    asm("v_cvt_pk_bf16_f32 %0, %1, %2" : "=v"(w2) : "v"(p[4]),  "v"(p[5]));
    asm("v_cvt_pk_bf16_f32 %0, %1, %2" : "=v"(w3) : "v"(p[6]),  "v"(p[7]));
    asm("v_cvt_pk_bf16_f32 %0, %1, %2" : "=v"(w4) : "v"(p[8]),  "v"(p[9]));
    asm("v_cvt_pk_bf16_f32 %0, %1, %2" : "=v"(w5) : "v"(p[10]), "v"(p[11]));
    asm("v_cvt_pk_bf16_f32 %0, %1, %2" : "=v"(w6) : "v"(p[12]), "v"(p[13]));
    asm("v_cvt_pk_bf16_f32 %0, %1, %2" : "=v"(w7) : "v"(p[14]), "v"(p[15]));
    asm("v_permlane32_swap_b32 %0, %1" : "+v"(w0), "+v"(w2));
    asm("v_permlane32_swap_b32 %0, %1" : "+v"(w1), "+v"(w3));
    asm("v_permlane32_swap_b32 %0, %1" : "+v"(w4), "+v"(w6));
    asm("v_permlane32_swap_b32 %0, %1" : "+v"(w5), "+v"(w7));
    union { unsigned u[4]; bf16x8 v; } pb0, pb1;
    pb0.u[0] = w0; pb0.u[1] = w1; pb0.u[2] = w2; pb0.u[3] = w3;
    pb1.u[0] = w4; pb1.u[1] = w5; pb1.u[2] = w6; pb1.u[3] = w7;

    // O^T[dt] += V^T[dt][k] . P^T[k][q]
    const u16* vr = VT + (size_t)(bh * HS + l31) * TSEQ + kt * 32 + hh * 8;
    bf16x8 vf00 = *reinterpret_cast<const bf16x8*>(vr);
    bf16x8 vf01 = *reinterpret_cast<const bf16x8*>(vr + 16);
    bf16x8 vf10 = *reinterpret_cast<const bf16x8*>(vr + 32 * TSEQ);
    bf16x8 vf11 = *reinterpret_cast<const bf16x8*>(vr + 32 * TSEQ + 16);
    of[0] = __builtin_amdgcn_mfma_f32_32x32x16_bf16(vf00, pb0.v, of[0], 0, 0, 0);
    of[0] = __builtin_amdgcn_mfma_f32_32x32x16_bf16(vf01, pb1.v, of[0], 0, 0, 0);
    of[1] = __builtin_amdgcn_mfma_f32_32x32x16_bf16(vf10, pb0.v, of[1], 0, 0, 0);
    of[1] = __builtin_amdgcn_mfma_f32_32x32x16_bf16(vf11, pb1.v, of[1], 0, 0, 0);
  }

  float inv = 1.0f / lsum;
  u16* obase = att + (size_t)(b * TSEQ + q0 + l31) * CDIM + h * HS;
#pragma unroll
  for (int dt = 0; dt < 2; ++dt)
#pragma unroll
    for (int i = 0; i < 8; ++i) {
      ushort2 st;
      st.x = f2b(of[dt][2 * i] * inv);
      st.y = f2b(of[dt][2 * i + 1] * inv);
      int d = dt * 32 + ((2 * i) & 3) + 8 * ((2 * i) >> 2) + 4 * hh;
      *reinterpret_cast<ushort2*>(obase + d) = st;
    }
}

// ---------------- output projection (m97 structure) ----------------
__global__ __launch_bounds__(256) void out_gemm(const u16* __restrict__ A,
                                                const u16* __restrict__ WT,
                                                const float* __restrict__ bias,
                                                float* __restrict__ out) {
  __shared__ __align__(16) u16 lsA[BM * BK];
  __shared__ __align__(16) u16 lsB[BN * BK];
  const int tid = threadIdx.x;
  const int lane = tid & 63;
  const int l16 = lane & 15, lg = lane >> 4;
  const int wid = tid >> 6;
  const int wr = wid >> 1, wc = wid & 1;
  const int m0 = blockIdx.x * BM;
  const int n0 = blockIdx.y * BN;

  const u16* gA = A + (size_t)m0 * CDIM;
  const u16* gB = WT + (size_t)n0 * CDIM;

  f32x4 acc[4][4] = {};

  for (int kt = 0; kt < CDIM; kt += BK) {
#pragma unroll
    for (int c = 0; c < 2; ++c) {
      int flat = c * 2048 + tid * 8;
      int row = flat >> 5, col = flat & 31;
      gload_lds16(gA + (size_t)row * CDIM + kt + col, lsA + flat);
      gload_lds16(gB + (size_t)row * CDIM + kt + col, lsB + flat);
    }
    __syncthreads();
    bf16x8 af[4], bfr[4];
#pragma unroll
    for (int m = 0; m < 4; ++m)
      af[m] = *reinterpret_cast<const bf16x8*>(lsA + (wr * 64 + m * 16 + l16) * BK + lg * 8);
#pragma unroll
    for (int n = 0; n < 4; ++n)
      bfr[n] = *reinterpret_cast<const bf16x8*>(lsB + (wc * 64 + n * 16 + l16) * BK + lg * 8);
#pragma unroll
    for (int m = 0; m < 4; ++m)
#pragma unroll
      for (int n = 0; n < 4; ++n)
        acc[m][n] = __builtin_amdgcn_mfma_f32_16x16x32_bf16(af[m], bfr[n], acc[m][n], 0, 0, 0);
    __syncthreads();
  }

#pragma unroll
  for (int n = 0; n < 4; ++n) {
    int col = n0 + wc * 64 + n * 16 + l16;
    float bv = bias[col];
#pragma unroll
    for (int m = 0; m < 4; ++m)
#pragma unroll
      for (int r = 0; r < 4; ++r) {
        int row = m0 + wr * 64 + m * 16 + lg * 4 + r;
        out[(size_t)row * CDIM + col] = acc[m][n][r] + bv;
      }
  }
}

// ---------------- launcher ----------------
extern "C" void kernel_launch(void* const* d_in, const int* in_sizes, int n_in,
                              void* d_out, int out_size, void* d_ws, size_t ws_size,
                              hipStream_t stream) {
  const float* x  = (const float*)d_in[0];
  const float* Wq = (const float*)d_in[1];
  const float* Wk = (const float*)d_in[2];
  const float* Wv = (const float*)d_in[3];
  const float* Wo = (const float*)d_in[4];
  const float* bo = (const float*)d_in[5];
  float* out = (float*)d_out;

  char* p = (char*)d_ws;
  const size_t big = (size_t)MROWS * CDIM * 2;     // 16.78 MB per bf16 activation
  u16* xb   = (u16*)p;  p += big;
  u16* wtA  = (u16*)p;  p += (size_t)3 * CDIM * CDIM * 2;
  u16* woT  = (u16*)p;  p += (size_t)CDIM * CDIM * 2;
  float* cosT = (float*)p; p += (size_t)TSEQ * 32 * 4;
  float* sinT = (float*)p; p += (size_t)TSEQ * 32 * 4;
  u16* Qb   = (u16*)p;  p += big;
  u16* Kb   = (u16*)p;  p += big;
  u16* VT   = (u16*)p;  p += big;
  u16* att  = (u16*)p;  p += big;

  hipLaunchKernelGGL(conv_x, dim3(MROWS * CDIM / 4 / 256), dim3(256), 0, stream, x, xb);
  hipLaunchKernelGGL(transpose_w, dim3(16, 16, 4), dim3(32, 8), 0, stream,
                     Wq, Wk, Wv, Wo, wtA, woT);
  hipLaunchKernelGGL(rope_tab, dim3(TSEQ * 32 / 256), dim3(256), 0, stream, cosT, sinT);
  hipLaunchKernelGGL(qkv_gemm, dim3(MROWS / BM, 1536 / BN), dim3(256), 0, stream,
                     xb, wtA, cosT, sinT, Qb, Kb, VT);
  hipLaunchKernelGGL(attn_kern, dim3(BBATCH * NH, TSEQ / 128), dim3(256), 0, stream,
                     Qb, Kb, VT, att);
  hipLaunchKernelGGL(out_gemm, dim3(MROWS / BM, CDIM / BN), dim3(256), 0, stream,
                     att, woT, bo, out);
}

// Round 5
// 123.638 us; speedup vs baseline: 1.2303x; 1.2303x over previous
//
#include <hip/hip_runtime.h>

#define TSEQ 512
#define CDIM 512
#define NH 8
#define HS 64
#define BBATCH 32
#define MROWS (BBATCH * TSEQ)   // 16384

#define BM 128
#define BN 128
#define BK 32
#define NKT (CDIM / BK)

typedef unsigned short u16;
typedef __bf16 bf16x8 __attribute__((ext_vector_type(8)));
typedef float f32x4 __attribute__((ext_vector_type(4)));
typedef float f32x16 __attribute__((ext_vector_type(16)));

// round-to-nearest-even fp32 -> bf16 bits
__device__ __forceinline__ u16 f2b(float f) {
  union { float f; unsigned u; } v; v.f = f;
  unsigned r = (v.u + 0x7fffu + ((v.u >> 16) & 1u)) >> 16;
  return (u16)r;
}

__device__ __forceinline__ void gload_lds16(const u16* g, u16* l) {
  __builtin_amdgcn_global_load_lds(
      (const __attribute__((address_space(1))) void*)g,
      (__attribute__((address_space(3))) void*)l, 16, 0, 0);
}

// ---------------- prep kernels ----------------

__global__ __launch_bounds__(256) void conv_x(const float* __restrict__ x,
                                              u16* __restrict__ xb) {
  int i = blockIdx.x * 256 + threadIdx.x;       // MROWS*CDIM/4 elements
  float4 v = reinterpret_cast<const float4*>(x)[i];
  ushort4 o;
  o.x = f2b(v.x); o.y = f2b(v.y); o.z = f2b(v.z); o.w = f2b(v.w);
  reinterpret_cast<ushort4*>(xb)[i] = o;
}

// transpose Wq,Wk,Wv -> wtA[1536][512] bf16 ; Wo -> woT[512][512] bf16
__global__ __launch_bounds__(256) void transpose_w(const float* __restrict__ wq,
                                                   const float* __restrict__ wk,
                                                   const float* __restrict__ wv,
                                                   const float* __restrict__ wo,
                                                   u16* __restrict__ wtA,
                                                   u16* __restrict__ woT) {
  __shared__ float tile[32][33];
  int mat = blockIdx.z;
  const float* src = (mat == 0) ? wq : (mat == 1) ? wk : (mat == 2) ? wv : wo;
  u16* dst = (mat < 3) ? (wtA + (size_t)mat * CDIM * CDIM) : woT;
  int kb = blockIdx.x * 32, nb = blockIdx.y * 32;
  int tx = threadIdx.x, ty = threadIdx.y;
#pragma unroll
  for (int rr = 0; rr < 32; rr += 8)
    tile[ty + rr][tx] = src[(size_t)(kb + ty + rr) * CDIM + nb + tx];
  __syncthreads();
#pragma unroll
  for (int rr = 0; rr < 32; rr += 8)
    dst[(size_t)(nb + ty + rr) * CDIM + kb + tx] = f2b(tile[tx][ty + rr]);
}

__global__ __launch_bounds__(256) void rope_tab(float* __restrict__ cosT,
                                                float* __restrict__ sinT) {
  int i = blockIdx.x * 256 + threadIdx.x;       // 512*32
  int t = i >> 5, f = i & 31;
  float inv = __powf(10000.0f, -(float)f / 32.0f);
  float ang = (float)t * inv;
  cosT[i] = cosf(ang);
  sinT[i] = sinf(ang);
}

// V natural [B*T][512-col where col=h*64+d] -> VT [(b*8+h)*64+d][512 t]
__global__ __launch_bounds__(256) void vt_t(const u16* __restrict__ Vb,
                                            u16* __restrict__ VT) {
  __shared__ __align__(16) u16 tile[64][72];   // 72: 144B row stride, 16B-aligned
  const int bh = blockIdx.x;                   // 0..255
  const int b = bh >> 3, h = bh & 7;
  const int tt = blockIdx.y;                   // 0..7, 64 t per tile
  const int tid = threadIdx.x;
#pragma unroll
  for (int p = 0; p < 2; ++p) {
    int tl = (tid >> 3) + p * 32;              // t-local 0..63
    int dc = tid & 7;                          // d-chunk of 8
    const u16* src = Vb + (size_t)(b * TSEQ + tt * 64 + tl) * CDIM + h * HS + dc * 8;
    ushort4 v0 = *reinterpret_cast<const ushort4*>(src);
    ushort4 v1 = *reinterpret_cast<const ushort4*>(src + 4);
    tile[dc * 8 + 0][tl] = v0.x; tile[dc * 8 + 1][tl] = v0.y;
    tile[dc * 8 + 2][tl] = v0.z; tile[dc * 8 + 3][tl] = v0.w;
    tile[dc * 8 + 4][tl] = v1.x; tile[dc * 8 + 5][tl] = v1.y;
    tile[dc * 8 + 6][tl] = v1.z; tile[dc * 8 + 7][tl] = v1.w;
  }
  __syncthreads();
#pragma unroll
  for (int p = 0; p < 2; ++p) {
    int d = (tid >> 3) + p * 32;
    int tc = tid & 7;
    int4 vdat = *reinterpret_cast<const int4*>(&tile[d][tc * 8]);
    *reinterpret_cast<int4*>(VT + (size_t)(bh * HS + d) * TSEQ + tt * 64 + tc * 8) = vdat;
  }
}

// ---------------- fused QKV GEMM + RoPE (m97 + 2-phase dbuf) ----------------
__global__ __launch_bounds__(256) void qkv_gemm(const u16* __restrict__ xb,
                                                const u16* __restrict__ wtA,
                                                const float* __restrict__ cosT,
                                                const float* __restrict__ sinT,
                                                u16* __restrict__ Qb,
                                                u16* __restrict__ Kb,
                                                u16* __restrict__ Vb) {
  __shared__ __align__(16) u16 smem[2][BM * BK + BN * BK];   // 32 KB
  const int tid = threadIdx.x;
  const int lane = tid & 63;
  const int l16 = lane & 15, lg = lane >> 4;
  const int wid = tid >> 6;
  const int wr = wid >> 1, wc = wid & 1;
  const int m0 = blockIdx.x * BM;
  const int n0 = blockIdx.y * BN;

  const u16* gA = xb + (size_t)m0 * CDIM;
  const u16* gB = wtA + (size_t)n0 * CDIM;

  f32x4 acc[4][4] = {};

  auto stage = [&](int buf, int k0) {
#pragma unroll
    for (int c = 0; c < 2; ++c) {
      int flat = c * 2048 + tid * 8;           // element index in 128x32 tile
      int row = flat >> 5, col = flat & 31;
      gload_lds16(gA + (size_t)row * CDIM + k0 + col, &smem[buf][flat]);
      gload_lds16(gB + (size_t)row * CDIM + k0 + col, &smem[buf][BM * BK + flat]);
    }
  };

  stage(0, 0);
  __syncthreads();
  int cur = 0;
  for (int kt = 0; kt < NKT; ++kt) {
    if (kt + 1 < NKT) stage(cur ^ 1, (kt + 1) * BK);   // prefetch BEFORE compute
    const u16* lsA = &smem[cur][0];
    const u16* lsB = &smem[cur][BM * BK];
    bf16x8 af[4], bfr[4];
#pragma unroll
    for (int m = 0; m < 4; ++m)
      af[m] = *reinterpret_cast<const bf16x8*>(lsA + (wr * 64 + m * 16 + l16) * BK + lg * 8);
#pragma unroll
    for (int n = 0; n < 4; ++n)
      bfr[n] = *reinterpret_cast<const bf16x8*>(lsB + (wc * 64 + n * 16 + l16) * BK + lg * 8);
#pragma unroll
    for (int m = 0; m < 4; ++m)
#pragma unroll
      for (int n = 0; n < 4; ++n)
        acc[m][n] = __builtin_amdgcn_mfma_f32_16x16x32_bf16(af[m], bfr[n], acc[m][n], 0, 0, 0);
    __syncthreads();   // drains vmcnt (next buf landed) + all ds_reads of cur done
    cur ^= 1;
  }

  // ---- epilogue: RoPE for Q/K, natural coalesced-region store for V ----
  const int gcolbase = n0 + wc * 64;
  const int mat = gcolbase >> 9;               // 0:Q 1:K 2:V (block-uniform)
  if (mat < 2) {
    u16* dst = (mat == 0) ? Qb : Kb;
#pragma unroll
    for (int n = 0; n < 4; ++n) {
      int gcol = gcolbase + n * 16 + l16;
      int nc = gcol & 511;
      int dd = nc & 63;
      int fi = dd >> 1;
#pragma unroll
      for (int m = 0; m < 4; ++m)
#pragma unroll
        for (int r = 0; r < 4; ++r) {
          int row = m0 + wr * 64 + m * 16 + lg * 4 + r;
          int t = row & (TSEQ - 1);
          float v = acc[m][n][r];
          float o = __shfl_xor(v, 1);          // RoPE partner column
          float c = cosT[t * 32 + fi];
          float sn = sinT[t * 32 + fi];
          float res = (dd & 1) ? (v * c + o * sn) : (v * c - o * sn);
          dst[(size_t)row * CDIM + nc] = f2b(res);
        }
    }
  } else {
#pragma unroll
    for (int n = 0; n < 4; ++n) {
      int nc = (gcolbase + n * 16 + l16) & 511;
#pragma unroll
      for (int m = 0; m < 4; ++m)
#pragma unroll
        for (int r = 0; r < 4; ++r) {
          int row = m0 + wr * 64 + m * 16 + lg * 4 + r;
          Vb[(size_t)row * CDIM + nc] = f2b(acc[m][n][r]);
        }
    }
  }
}

// ---------------- flash attention (swapped QK^T, 32x32 MFMA, no LDS) -------
// grid (B*H, TSEQ/128), block 256 (4 waves). Each wave: 32 q-rows, lane owns
// ONE q-column (q = q0 + (lane&31)); softmax is lane-local.
__global__ __launch_bounds__(256, 4) void attn_kern(const u16* __restrict__ Qb,
                                                    const u16* __restrict__ Kb,
                                                    const u16* __restrict__ VT,
                                                    u16* __restrict__ att) {
  const int lane = threadIdx.x & 63, wid = threadIdx.x >> 6;
  const int l31 = lane & 31, hh = lane >> 5;
  const int bh = blockIdx.x, b = bh >> 3, h = bh & 7;
  const int q0 = blockIdx.y * 128 + wid * 32;

  bf16x8 qf[4];
  const u16* qbase = Qb + (size_t)(b * TSEQ + q0 + l31) * CDIM + h * HS + hh * 8;
#pragma unroll
  for (int ds = 0; ds < 4; ++ds)
    qf[ds] = *reinterpret_cast<const bf16x8*>(qbase + ds * 16);

  const float SC = 0.125f * 1.4426950408889634f;  // scale * log2(e)
  float m_r = -1e30f, lsum = 0.0f;
  f32x16 of[2] = {};   // O^T[d][q]: of[dt], d = dt*32 + (r&3)+8*(r>>2)+4*hh

  const int nkt = (q0 >> 5) + 1;
  for (int kt = 0; kt < nkt; ++kt) {
    // S^T[k][q] = mfma(K as A, Q as B)
    f32x16 s = {};
    const u16* kr = Kb + (size_t)(b * TSEQ + kt * 32 + l31) * CDIM + h * HS + hh * 8;
#pragma unroll
    for (int ds = 0; ds < 4; ++ds) {
      bf16x8 kf = *reinterpret_cast<const bf16x8*>(kr + ds * 16);
      s = __builtin_amdgcn_mfma_f32_32x32x16_bf16(kf, qf[ds], s, 0, 0, 0);
    }
    float p[16];
#pragma unroll
    for (int r = 0; r < 16; ++r) p[r] = s[r] * SC;
    if (kt == nkt - 1) {          // diagonal tile: mask k > q
#pragma unroll
      for (int r = 0; r < 16; ++r) {
        int kk = (r & 3) + 8 * (r >> 2) + 4 * hh;
        if (kk > l31) p[r] = -1e30f;
      }
    }
    float pm = p[0];
#pragma unroll
    for (int r = 1; r < 16; ++r) pm = fmaxf(pm, p[r]);
    pm = fmaxf(pm, __shfl_xor(pm, 32));
    if (!__all(pm - m_r <= 8.0f)) {   // T13 defer-max
      float mn = fmaxf(m_r, pm);
      float alpha = exp2f(m_r - mn);
      m_r = mn;
      lsum *= alpha;
#pragma unroll
      for (int r = 0; r < 16; ++r) { of[0][r] *= alpha; of[1][r] *= alpha; }
    }
    float ts = 0.0f;
#pragma unroll
    for (int r = 0; r < 16; ++r) { p[r] = exp2f(p[r] - m_r); ts += p[r]; }
    ts += __shfl_xor(ts, 32);
    lsum += ts;

    // P^T -> bf16 B-fragments via cvt_pk + permlane32_swap (T12)
    unsigned w0, w1, w2, w3, w4, w5, w6, w7;
    asm("v_cvt_pk_bf16_f32 %0, %1, %2" : "=v"(w0) : "v"(p[0]),  "v"(p[1]));
    asm("v_cvt_pk_bf16_f32 %0, %1, %2" : "=v"(w1) : "v"(p[2]),  "v"(p[3]));
    asm("v_cvt_pk_bf16_f32 %0, %1, %2" : "=v"(w2) : "v"(p[4]),  "v"(p[5]));
    asm("v_cvt_pk_bf16_f32 %0, %1, %2" : "=v"(w3) : "v"(p[6]),  "v"(p[7]));
    asm("v_cvt_pk_bf16_f32 %0, %1, %2" : "=v"(w4) : "v"(p[8]),  "v"(p[9]));
    asm("v_cvt_pk_bf16_f32 %0, %1, %2" : "=v"(w5) : "v"(p[10]), "v"(p[11]));
    asm("v_cvt_pk_bf16_f32 %0, %1, %2" : "=v"(w6) : "v"(p[12]), "v"(p[13]));
    asm("v_cvt_pk_bf16_f32 %0, %1, %2" : "=v"(w7) : "v"(p[14]), "v"(p[15]));
    asm("v_permlane32_swap_b32 %0, %1" : "+v"(w0), "+v"(w2));
    asm("v_permlane32_swap_b32 %0, %1" : "+v"(w1), "+v"(w3));
    asm("v_permlane32_swap_b32 %0, %1" : "+v"(w4), "+v"(w6));
    asm("v_permlane32_swap_b32 %0, %1" : "+v"(w5), "+v"(w7));
    union { unsigned u[4]; bf16x8 v; } pb0, pb1;
    pb0.u[0] = w0; pb0.u[1] = w1; pb0.u[2] = w2; pb0.u[3] = w3;
    pb1.u[0] = w4; pb1.u[1] = w5; pb1.u[2] = w6; pb1.u[3] = w7;

    // O^T[dt] += V^T[dt][k] . P^T[k][q]
    const u16* vr = VT + (size_t)(bh * HS + l31) * TSEQ + kt * 32 + hh * 8;
    bf16x8 vf00 = *reinterpret_cast<const bf16x8*>(vr);
    bf16x8 vf01 = *reinterpret_cast<const bf16x8*>(vr + 16);
    bf16x8 vf10 = *reinterpret_cast<const bf16x8*>(vr + 32 * TSEQ);
    bf16x8 vf11 = *reinterpret_cast<const bf16x8*>(vr + 32 * TSEQ + 16);
    of[0] = __builtin_amdgcn_mfma_f32_32x32x16_bf16(vf00, pb0.v, of[0], 0, 0, 0);
    of[0] = __builtin_amdgcn_mfma_f32_32x32x16_bf16(vf01, pb1.v, of[0], 0, 0, 0);
    of[1] = __builtin_amdgcn_mfma_f32_32x32x16_bf16(vf10, pb0.v, of[1], 0, 0, 0);
    of[1] = __builtin_amdgcn_mfma_f32_32x32x16_bf16(vf11, pb1.v, of[1], 0, 0, 0);
  }

  float inv = 1.0f / lsum;
  u16* obase = att + (size_t)(b * TSEQ + q0 + l31) * CDIM + h * HS;
#pragma unroll
  for (int dt = 0; dt < 2; ++dt)
#pragma unroll
    for (int i = 0; i < 8; ++i) {
      ushort2 st;
      st.x = f2b(of[dt][2 * i] * inv);
      st.y = f2b(of[dt][2 * i + 1] * inv);
      int d = dt * 32 + ((2 * i) & 3) + 8 * ((2 * i) >> 2) + 4 * hh;
      *reinterpret_cast<ushort2*>(obase + d) = st;
    }
}

// ---------------- output projection (m97 + 2-phase dbuf) ----------------
__global__ __launch_bounds__(256) void out_gemm(const u16* __restrict__ A,
                                                const u16* __restrict__ WT,
                                                const float* __restrict__ bias,
                                                float* __restrict__ out) {
  __shared__ __align__(16) u16 smem[2][BM * BK + BN * BK];
  const int tid = threadIdx.x;
  const int lane = tid & 63;
  const int l16 = lane & 15, lg = lane >> 4;
  const int wid = tid >> 6;
  const int wr = wid >> 1, wc = wid & 1;
  const int m0 = blockIdx.x * BM;
  const int n0 = blockIdx.y * BN;

  const u16* gA = A + (size_t)m0 * CDIM;
  const u16* gB = WT + (size_t)n0 * CDIM;

  f32x4 acc[4][4] = {};

  auto stage = [&](int buf, int k0) {
#pragma unroll
    for (int c = 0; c < 2; ++c) {
      int flat = c * 2048 + tid * 8;
      int row = flat >> 5, col = flat & 31;
      gload_lds16(gA + (size_t)row * CDIM + k0 + col, &smem[buf][flat]);
      gload_lds16(gB + (size_t)row * CDIM + k0 + col, &smem[buf][BM * BK + flat]);
    }
  };

  stage(0, 0);
  __syncthreads();
  int cur = 0;
  for (int kt = 0; kt < NKT; ++kt) {
    if (kt + 1 < NKT) stage(cur ^ 1, (kt + 1) * BK);
    const u16* lsA = &smem[cur][0];
    const u16* lsB = &smem[cur][BM * BK];
    bf16x8 af[4], bfr[4];
#pragma unroll
    for (int m = 0; m < 4; ++m)
      af[m] = *reinterpret_cast<const bf16x8*>(lsA + (wr * 64 + m * 16 + l16) * BK + lg * 8);
#pragma unroll
    for (int n = 0; n < 4; ++n)
      bfr[n] = *reinterpret_cast<const bf16x8*>(lsB + (wc * 64 + n * 16 + l16) * BK + lg * 8);
#pragma unroll
    for (int m = 0; m < 4; ++m)
#pragma unroll
      for (int n = 0; n < 4; ++n)
        acc[m][n] = __builtin_amdgcn_mfma_f32_16x16x32_bf16(af[m], bfr[n], acc[m][n], 0, 0, 0);
    __syncthreads();
    cur ^= 1;
  }

#pragma unroll
  for (int n = 0; n < 4; ++n) {
    int col = n0 + wc * 64 + n * 16 + l16;
    float bv = bias[col];
#pragma unroll
    for (int m = 0; m < 4; ++m)
#pragma unroll
      for (int r = 0; r < 4; ++r) {
        int row = m0 + wr * 64 + m * 16 + lg * 4 + r;
        out[(size_t)row * CDIM + col] = acc[m][n][r] + bv;
      }
  }
}

// ---------------- launcher ----------------
extern "C" void kernel_launch(void* const* d_in, const int* in_sizes, int n_in,
                              void* d_out, int out_size, void* d_ws, size_t ws_size,
                              hipStream_t stream) {
  const float* x  = (const float*)d_in[0];
  const float* Wq = (const float*)d_in[1];
  const float* Wk = (const float*)d_in[2];
  const float* Wv = (const float*)d_in[3];
  const float* Wo = (const float*)d_in[4];
  const float* bo = (const float*)d_in[5];
  float* out = (float*)d_out;

  char* p = (char*)d_ws;
  const size_t big = (size_t)MROWS * CDIM * 2;     // 16.78 MB per bf16 activation
  u16* xb   = (u16*)p;  p += big;
  u16* wtA  = (u16*)p;  p += (size_t)3 * CDIM * CDIM * 2;
  u16* woT  = (u16*)p;  p += (size_t)CDIM * CDIM * 2;
  float* cosT = (float*)p; p += (size_t)TSEQ * 32 * 4;
  float* sinT = (float*)p; p += (size_t)TSEQ * 32 * 4;
  u16* Qb   = (u16*)p;  p += big;
  u16* Kb   = (u16*)p;  p += big;
  u16* VT   = (u16*)p;  p += big;
  u16* att  = (u16*)p;  p += big;   // att aliases Vb: Vb dead before attn writes
  u16* Vb   = att;

  hipLaunchKernelGGL(conv_x, dim3(MROWS * CDIM / 4 / 256), dim3(256), 0, stream, x, xb);
  hipLaunchKernelGGL(transpose_w, dim3(16, 16, 4), dim3(32, 8), 0, stream,
                     Wq, Wk, Wv, Wo, wtA, woT);
  hipLaunchKernelGGL(rope_tab, dim3(TSEQ * 32 / 256), dim3(256), 0, stream, cosT, sinT);
  hipLaunchKernelGGL(qkv_gemm, dim3(MROWS / BM, 1536 / BN), dim3(256), 0, stream,
                     xb, wtA, cosT, sinT, Qb, Kb, Vb);
  hipLaunchKernelGGL(vt_t, dim3(BBATCH * NH, TSEQ / 64), dim3(256), 0, stream, Vb, VT);
  hipLaunchKernelGGL(attn_kern, dim3(BBATCH * NH, TSEQ / 128), dim3(256), 0, stream,
                     Qb, Kb, VT, att);
  hipLaunchKernelGGL(out_gemm, dim3(MROWS / BM, CDIM / BN), dim3(256), 0, stream,
                     att, woT, bo, out);
}

// Round 7
// 122.943 us; speedup vs baseline: 1.2373x; 1.0056x over previous
//
#include <hip/hip_runtime.h>

#define TSEQ 512
#define CDIM 512
#define NH 8
#define HS 64
#define BBATCH 32
#define MROWS (BBATCH * TSEQ)   // 16384

#define BM 128
#define BN 128
#define BK 32
#define NKT (CDIM / BK)

typedef unsigned short u16;
typedef __bf16 bf16x8 __attribute__((ext_vector_type(8)));
typedef float f32x4 __attribute__((ext_vector_type(4)));
typedef float f32x16 __attribute__((ext_vector_type(16)));

// round-to-nearest-even fp32 -> bf16 bits
__device__ __forceinline__ u16 f2b(float f) {
  union { float f; unsigned u; } v; v.f = f;
  unsigned r = (v.u + 0x7fffu + ((v.u >> 16) & 1u)) >> 16;
  return (u16)r;
}

__device__ __forceinline__ void gload_lds16(const u16* g, u16* l) {
  __builtin_amdgcn_global_load_lds(
      (const __attribute__((address_space(1))) void*)g,
      (__attribute__((address_space(3))) void*)l, 16, 0, 0);
}

// ---------------- prep kernels ----------------

__global__ __launch_bounds__(256) void conv_x(const float* __restrict__ x,
                                              u16* __restrict__ xb) {
  int i = blockIdx.x * 256 + threadIdx.x;       // MROWS*CDIM/4 elements
  float4 v = reinterpret_cast<const float4*>(x)[i];
  ushort4 o;
  o.x = f2b(v.x); o.y = f2b(v.y); o.z = f2b(v.z); o.w = f2b(v.w);
  reinterpret_cast<ushort4*>(xb)[i] = o;
}

// transpose Wq,Wk,Wv -> wtA[1536][512] bf16 ; Wo -> woT[512][512] bf16
__global__ __launch_bounds__(256) void transpose_w(const float* __restrict__ wq,
                                                   const float* __restrict__ wk,
                                                   const float* __restrict__ wv,
                                                   const float* __restrict__ wo,
                                                   u16* __restrict__ wtA,
                                                   u16* __restrict__ woT) {
  __shared__ float tile[32][33];
  int mat = blockIdx.z;
  const float* src = (mat == 0) ? wq : (mat == 1) ? wk : (mat == 2) ? wv : wo;
  u16* dst = (mat < 3) ? (wtA + (size_t)mat * CDIM * CDIM) : woT;
  int kb = blockIdx.x * 32, nb = blockIdx.y * 32;
  int tx = threadIdx.x, ty = threadIdx.y;
#pragma unroll
  for (int rr = 0; rr < 32; rr += 8)
    tile[ty + rr][tx] = src[(size_t)(kb + ty + rr) * CDIM + nb + tx];
  __syncthreads();
#pragma unroll
  for (int rr = 0; rr < 32; rr += 8)
    dst[(size_t)(nb + ty + rr) * CDIM + kb + tx] = f2b(tile[tx][ty + rr]);
}

__global__ __launch_bounds__(256) void rope_tab(float* __restrict__ cosT,
                                                float* __restrict__ sinT) {
  int i = blockIdx.x * 256 + threadIdx.x;       // 512*32
  int t = i >> 5, f = i & 31;
  float inv = __powf(10000.0f, -(float)f / 32.0f);
  float ang = (float)t * inv;
  cosT[i] = cosf(ang);
  sinT[i] = sinf(ang);
}

// V natural [B*T][512-col where col=h*64+d] -> VT [(b*8+h)*64+d][512 t]
__global__ __launch_bounds__(256) void vt_t(const u16* __restrict__ Vb,
                                            u16* __restrict__ VT) {
  __shared__ __align__(16) u16 tile[64][72];   // 72: 144B row stride, 16B-aligned
  const int bh = blockIdx.x;                   // 0..255
  const int b = bh >> 3, h = bh & 7;
  const int tt = blockIdx.y;                   // 0..7, 64 t per tile
  const int tid = threadIdx.x;
#pragma unroll
  for (int p = 0; p < 2; ++p) {
    int tl = (tid >> 3) + p * 32;              // t-local 0..63
    int dc = tid & 7;                          // d-chunk of 8
    const u16* src = Vb + (size_t)(b * TSEQ + tt * 64 + tl) * CDIM + h * HS + dc * 8;
    ushort4 v0 = *reinterpret_cast<const ushort4*>(src);
    ushort4 v1 = *reinterpret_cast<const ushort4*>(src + 4);
    tile[dc * 8 + 0][tl] = v0.x; tile[dc * 8 + 1][tl] = v0.y;
    tile[dc * 8 + 2][tl] = v0.z; tile[dc * 8 + 3][tl] = v0.w;
    tile[dc * 8 + 4][tl] = v1.x; tile[dc * 8 + 5][tl] = v1.y;
    tile[dc * 8 + 6][tl] = v1.z; tile[dc * 8 + 7][tl] = v1.w;
  }
  __syncthreads();
#pragma unroll
  for (int p = 0; p < 2; ++p) {
    int d = (tid >> 3) + p * 32;
    int tc = tid & 7;
    int4 vdat = *reinterpret_cast<const int4*>(&tile[d][tc * 8]);
    *reinterpret_cast<int4*>(VT + (size_t)(bh * HS + d) * TSEQ + tt * 64 + tc * 8) = vdat;
  }
}

// ---------------- fused QKV GEMM + RoPE (2-phase dbuf, counted vmcnt, pinned)
__global__ __launch_bounds__(256) void qkv_gemm(const u16* __restrict__ xb,
                                                const u16* __restrict__ wtA,
                                                const float* __restrict__ cosT,
                                                const float* __restrict__ sinT,
                                                u16* __restrict__ Qb,
                                                u16* __restrict__ Kb,
                                                u16* __restrict__ Vb) {
  __shared__ __align__(16) u16 smem[2][BM * BK + BN * BK];   // 32 KB
  const int tid = threadIdx.x;
  const int lane = tid & 63;
  const int l16 = lane & 15, lg = lane >> 4;
  const int wid = tid >> 6;
  const int wr = wid >> 1, wc = wid & 1;
  const int m0 = blockIdx.x * BM;
  const int n0 = blockIdx.y * BN;

  const u16* gA = xb + (size_t)m0 * CDIM;
  const u16* gB = wtA + (size_t)n0 * CDIM;

  f32x4 acc[4][4] = {};

  auto stage = [&](int buf, int k0) {
#pragma unroll
    for (int c = 0; c < 2; ++c) {
      int flat = c * 2048 + tid * 8;           // element index in 128x32 tile
      int row = flat >> 5, col = flat & 31;
      gload_lds16(gA + (size_t)row * CDIM + k0 + col, &smem[buf][flat]);
      gload_lds16(gB + (size_t)row * CDIM + k0 + col, &smem[buf][BM * BK + flat]);
    }
  };

  stage(0, 0);                       // 4 loads in flight
  int cur = 0;
  for (int kt = 0; kt < NKT; ++kt) {
    if (kt + 1 < NKT) {
      stage(cur ^ 1, (kt + 1) * BK); // +4 loads -> 8 in flight
      asm volatile("s_waitcnt vmcnt(4)" ::: "memory");  // wait stage(cur) only
    } else {
      asm volatile("s_waitcnt vmcnt(0)" ::: "memory");  // final tile: drain
    }
    // Raw s_barrier is NOT a compiler fence: pin both sides (rule #18 class).
    __builtin_amdgcn_sched_barrier(0);
    __builtin_amdgcn_s_barrier();
    __builtin_amdgcn_sched_barrier(0);
    const u16* lsA = &smem[cur][0];
    const u16* lsB = &smem[cur][BM * BK];
    bf16x8 af[4], bfr[4];
#pragma unroll
    for (int m = 0; m < 4; ++m)
      af[m] = *reinterpret_cast<const bf16x8*>(lsA + (wr * 64 + m * 16 + l16) * BK + lg * 8);
#pragma unroll
    for (int n = 0; n < 4; ++n)
      bfr[n] = *reinterpret_cast<const bf16x8*>(lsB + (wc * 64 + n * 16 + l16) * BK + lg * 8);
#pragma unroll
    for (int m = 0; m < 4; ++m)
#pragma unroll
      for (int n = 0; n < 4; ++n)
        acc[m][n] = __builtin_amdgcn_mfma_f32_16x16x32_bf16(af[m], bfr[n], acc[m][n], 0, 0, 0);
    // ds_reads complete before the MFMAs that consume them (compiler lgkmcnt);
    // pin so they cannot sink past the barrier into the next stage() overwrite.
    __builtin_amdgcn_sched_barrier(0);
    __builtin_amdgcn_s_barrier();
    __builtin_amdgcn_sched_barrier(0);
    cur ^= 1;
  }

  // ---- epilogue: RoPE for Q/K, natural coalesced-region store for V ----
  const int gcolbase = n0 + wc * 64;
  const int mat = gcolbase >> 9;               // 0:Q 1:K 2:V (block-uniform)
  if (mat < 2) {
    u16* dst = (mat == 0) ? Qb : Kb;
#pragma unroll
    for (int n = 0; n < 4; ++n) {
      int gcol = gcolbase + n * 16 + l16;
      int nc = gcol & 511;
      int dd = nc & 63;
      int fi = dd >> 1;
#pragma unroll
      for (int m = 0; m < 4; ++m)
#pragma unroll
        for (int r = 0; r < 4; ++r) {
          int row = m0 + wr * 64 + m * 16 + lg * 4 + r;
          int t = row & (TSEQ - 1);
          float v = acc[m][n][r];
          float o = __shfl_xor(v, 1);          // RoPE partner column
          float c = cosT[t * 32 + fi];
          float sn = sinT[t * 32 + fi];
          float res = (dd & 1) ? (v * c + o * sn) : (v * c - o * sn);
          dst[(size_t)row * CDIM + nc] = f2b(res);
        }
    }
  } else {
#pragma unroll
    for (int n = 0; n < 4; ++n) {
      int nc = (gcolbase + n * 16 + l16) & 511;
#pragma unroll
      for (int m = 0; m < 4; ++m)
#pragma unroll
        for (int r = 0; r < 4; ++r) {
          int row = m0 + wr * 64 + m * 16 + lg * 4 + r;
          Vb[(size_t)row * CDIM + nc] = f2b(acc[m][n][r]);
        }
    }
  }
}

// ---------------- flash attention (swapped QK^T, 32x32 MFMA, no LDS) -------
// grid (B*H, TSEQ/128), block 256 (4 waves). Each wave: 32 q-rows, lane owns
// ONE q-column (q = q0 + (lane&31)); softmax is lane-local.
__global__ __launch_bounds__(256, 4) void attn_kern(const u16* __restrict__ Qb,
                                                    const u16* __restrict__ Kb,
                                                    const u16* __restrict__ VT,
                                                    u16* __restrict__ att) {
  const int lane = threadIdx.x & 63, wid = threadIdx.x >> 6;
  const int l31 = lane & 31, hh = lane >> 5;
  const int bh = blockIdx.x, b = bh >> 3, h = bh & 7;
  const int q0 = blockIdx.y * 128 + wid * 32;

  bf16x8 qf[4];
  const u16* qbase = Qb + (size_t)(b * TSEQ + q0 + l31) * CDIM + h * HS + hh * 8;
#pragma unroll
  for (int ds = 0; ds < 4; ++ds)
    qf[ds] = *reinterpret_cast<const bf16x8*>(qbase + ds * 16);

  const float SC = 0.125f * 1.4426950408889634f;  // scale * log2(e)
  float m_r = -1e30f, lsum = 0.0f;
  f32x16 of[2] = {};   // O^T[d][q]: of[dt], d = dt*32 + (r&3)+8*(r>>2)+4*hh

  const int nkt = (q0 >> 5) + 1;
  for (int kt = 0; kt < nkt; ++kt) {
    // S^T[k][q] = mfma(K as A, Q as B)
    f32x16 s = {};
    const u16* kr = Kb + (size_t)(b * TSEQ + kt * 32 + l31) * CDIM + h * HS + hh * 8;
#pragma unroll
    for (int ds = 0; ds < 4; ++ds) {
      bf16x8 kf = *reinterpret_cast<const bf16x8*>(kr + ds * 16);
      s = __builtin_amdgcn_mfma_f32_32x32x16_bf16(kf, qf[ds], s, 0, 0, 0);
    }
    float p[16];
#pragma unroll
    for (int r = 0; r < 16; ++r) p[r] = s[r] * SC;
    if (kt == nkt - 1) {          // diagonal tile: mask k > q
#pragma unroll
      for (int r = 0; r < 16; ++r) {
        int kk = (r & 3) + 8 * (r >> 2) + 4 * hh;
        if (kk > l31) p[r] = -1e30f;
      }
    }
    float pm = p[0];
#pragma unroll
    for (int r = 1; r < 16; ++r) pm = fmaxf(pm, p[r]);
    pm = fmaxf(pm, __shfl_xor(pm, 32));
    if (!__all(pm - m_r <= 8.0f)) {   // T13 defer-max
      float mn = fmaxf(m_r, pm);
      float alpha = exp2f(m_r - mn);
      m_r = mn;
      lsum *= alpha;
#pragma unroll
      for (int r = 0; r < 16; ++r) { of[0][r] *= alpha; of[1][r] *= alpha; }
    }
    float ts = 0.0f;
#pragma unroll
    for (int r = 0; r < 16; ++r) { p[r] = exp2f(p[r] - m_r); ts += p[r]; }
    ts += __shfl_xor(ts, 32);
    lsum += ts;

    // P^T -> bf16 B-fragments via cvt_pk + permlane32_swap (T12)
    unsigned w0, w1, w2, w3, w4, w5, w6, w7;
    asm("v_cvt_pk_bf16_f32 %0, %1, %2" : "=v"(w0) : "v"(p[0]),  "v"(p[1]));
    asm("v_cvt_pk_bf16_f32 %0, %1, %2" : "=v"(w1) : "v"(p[2]),  "v"(p[3]));
    asm("v_cvt_pk_bf16_f32 %0, %1, %2" : "=v"(w2) : "v"(p[4]),  "v"(p[5]));
    asm("v_cvt_pk_bf16_f32 %0, %1, %2" : "=v"(w3) : "v"(p[6]),  "v"(p[7]));
    asm("v_cvt_pk_bf16_f32 %0, %1, %2" : "=v"(w4) : "v"(p[8]),  "v"(p[9]));
    asm("v_cvt_pk_bf16_f32 %0, %1, %2" : "=v"(w5) : "v"(p[10]), "v"(p[11]));
    asm("v_cvt_pk_bf16_f32 %0, %1, %2" : "=v"(w6) : "v"(p[12]), "v"(p[13]));
    asm("v_cvt_pk_bf16_f32 %0, %1, %2" : "=v"(w7) : "v"(p[14]), "v"(p[15]));
    asm("v_permlane32_swap_b32 %0, %1" : "+v"(w0), "+v"(w2));
    asm("v_permlane32_swap_b32 %0, %1" : "+v"(w1), "+v"(w3));
    asm("v_permlane32_swap_b32 %0, %1" : "+v"(w4), "+v"(w6));
    asm("v_permlane32_swap_b32 %0, %1" : "+v"(w5), "+v"(w7));
    union { unsigned u[4]; bf16x8 v; } pb0, pb1;
    pb0.u[0] = w0; pb0.u[1] = w1; pb0.u[2] = w2; pb0.u[3] = w3;
    pb1.u[0] = w4; pb1.u[1] = w5; pb1.u[2] = w6; pb1.u[3] = w7;

    // O^T[dt] += V^T[dt][k] . P^T[k][q]
    const u16* vr = VT + (size_t)(bh * HS + l31) * TSEQ + kt * 32 + hh * 8;
    bf16x8 vf00 = *reinterpret_cast<const bf16x8*>(vr);
    bf16x8 vf01 = *reinterpret_cast<const bf16x8*>(vr + 16);
    bf16x8 vf10 = *reinterpret_cast<const bf16x8*>(vr + 32 * TSEQ);
    bf16x8 vf11 = *reinterpret_cast<const bf16x8*>(vr + 32 * TSEQ + 16);
    of[0] = __builtin_amdgcn_mfma_f32_32x32x16_bf16(vf00, pb0.v, of[0], 0, 0, 0);
    of[0] = __builtin_amdgcn_mfma_f32_32x32x16_bf16(vf01, pb1.v, of[0], 0, 0, 0);
    of[1] = __builtin_amdgcn_mfma_f32_32x32x16_bf16(vf10, pb0.v, of[1], 0, 0, 0);
    of[1] = __builtin_amdgcn_mfma_f32_32x32x16_bf16(vf11, pb1.v, of[1], 0, 0, 0);
  }

  float inv = 1.0f / lsum;
  u16* obase = att + (size_t)(b * TSEQ + q0 + l31) * CDIM + h * HS;
#pragma unroll
  for (int dt = 0; dt < 2; ++dt)
#pragma unroll
    for (int i = 0; i < 8; ++i) {
      ushort2 st;
      st.x = f2b(of[dt][2 * i] * inv);
      st.y = f2b(of[dt][2 * i + 1] * inv);
      int d = dt * 32 + ((2 * i) & 3) + 8 * ((2 * i) >> 2) + 4 * hh;
      *reinterpret_cast<ushort2*>(obase + d) = st;
    }
}

// ---------------- output projection (2-phase dbuf, counted vmcnt, pinned) --
__global__ __launch_bounds__(256) void out_gemm(const u16* __restrict__ A,
                                                const u16* __restrict__ WT,
                                                const float* __restrict__ bias,
                                                float* __restrict__ out) {
  __shared__ __align__(16) u16 smem[2][BM * BK + BN * BK];
  const int tid = threadIdx.x;
  const int lane = tid & 63;
  const int l16 = lane & 15, lg = lane >> 4;
  const int wid = tid >> 6;
  const int wr = wid >> 1, wc = wid & 1;
  const int m0 = blockIdx.x * BM;
  const int n0 = blockIdx.y * BN;

  const u16* gA = A + (size_t)m0 * CDIM;
  const u16* gB = WT + (size_t)n0 * CDIM;

  f32x4 acc[4][4] = {};

  auto stage = [&](int buf, int k0) {
#pragma unroll
    for (int c = 0; c < 2; ++c) {
      int flat = c * 2048 + tid * 8;
      int row = flat >> 5, col = flat & 31;
      gload_lds16(gA + (size_t)row * CDIM + k0 + col, &smem[buf][flat]);
      gload_lds16(gB + (size_t)row * CDIM + k0 + col, &smem[buf][BM * BK + flat]);
    }
  };

  stage(0, 0);
  int cur = 0;
  for (int kt = 0; kt < NKT; ++kt) {
    if (kt + 1 < NKT) {
      stage(cur ^ 1, (kt + 1) * BK);
      asm volatile("s_waitcnt vmcnt(4)" ::: "memory");
    } else {
      asm volatile("s_waitcnt vmcnt(0)" ::: "memory");
    }
    __builtin_amdgcn_sched_barrier(0);
    __builtin_amdgcn_s_barrier();
    __builtin_amdgcn_sched_barrier(0);
    const u16* lsA = &smem[cur][0];
    const u16* lsB = &smem[cur][BM * BK];
    bf16x8 af[4], bfr[4];
#pragma unroll
    for (int m = 0; m < 4; ++m)
      af[m] = *reinterpret_cast<const bf16x8*>(lsA + (wr * 64 + m * 16 + l16) * BK + lg * 8);
#pragma unroll
    for (int n = 0; n < 4; ++n)
      bfr[n] = *reinterpret_cast<const bf16x8*>(lsB + (wc * 64 + n * 16 + l16) * BK + lg * 8);
#pragma unroll
    for (int m = 0; m < 4; ++m)
#pragma unroll
      for (int n = 0; n < 4; ++n)
        acc[m][n] = __builtin_amdgcn_mfma_f32_16x16x32_bf16(af[m], bfr[n], acc[m][n], 0, 0, 0);
    __builtin_amdgcn_sched_barrier(0);
    __builtin_amdgcn_s_barrier();
    __builtin_amdgcn_sched_barrier(0);
    cur ^= 1;
  }

#pragma unroll
  for (int n = 0; n < 4; ++n) {
    int col = n0 + wc * 64 + n * 16 + l16;
    float bv = bias[col];
#pragma unroll
    for (int m = 0; m < 4; ++m)
#pragma unroll
      for (int r = 0; r < 4; ++r) {
        int row = m0 + wr * 64 + m * 16 + lg * 4 + r;
        out[(size_t)row * CDIM + col] = acc[m][n][r] + bv;
      }
  }
}

// ---------------- launcher ----------------
extern "C" void kernel_launch(void* const* d_in, const int* in_sizes, int n_in,
                              void* d_out, int out_size, void* d_ws, size_t ws_size,
                              hipStream_t stream) {
  const float* x  = (const float*)d_in[0];
  const float* Wq = (const float*)d_in[1];
  const float* Wk = (const float*)d_in[2];
  const float* Wv = (const float*)d_in[3];
  const float* Wo = (const float*)d_in[4];
  const float* bo = (const float*)d_in[5];
  float* out = (float*)d_out;

  char* p = (char*)d_ws;
  const size_t big = (size_t)MROWS * CDIM * 2;     // 16.78 MB per bf16 activation
  u16* xb   = (u16*)p;  p += big;
  u16* wtA  = (u16*)p;  p += (size_t)3 * CDIM * CDIM * 2;
  u16* woT  = (u16*)p;  p += (size_t)CDIM * CDIM * 2;
  float* cosT = (float*)p; p += (size_t)TSEQ * 32 * 4;
  float* sinT = (float*)p; p += (size_t)TSEQ * 32 * 4;
  u16* Qb   = (u16*)p;  p += big;
  u16* Kb   = (u16*)p;  p += big;
  u16* VT   = (u16*)p;  p += big;
  u16* att  = (u16*)p;  p += big;   // att aliases Vb: Vb dead before attn writes
  u16* Vb   = att;

  hipLaunchKernelGGL(conv_x, dim3(MROWS * CDIM / 4 / 256), dim3(256), 0, stream, x, xb);
  hipLaunchKernelGGL(transpose_w, dim3(16, 16, 4), dim3(32, 8), 0, stream,
                     Wq, Wk, Wv, Wo, wtA, woT);
  hipLaunchKernelGGL(rope_tab, dim3(TSEQ * 32 / 256), dim3(256), 0, stream, cosT, sinT);
  hipLaunchKernelGGL(qkv_gemm, dim3(MROWS / BM, 1536 / BN), dim3(256), 0, stream,
                     xb, wtA, cosT, sinT, Qb, Kb, Vb);
  hipLaunchKernelGGL(vt_t, dim3(BBATCH * NH, TSEQ / 64), dim3(256), 0, stream, Vb, VT);
  hipLaunchKernelGGL(attn_kern, dim3(BBATCH * NH, TSEQ / 128), dim3(256), 0, stream,
                     Qb, Kb, VT, att);
  hipLaunchKernelGGL(out_gemm, dim3(MROWS / BM, CDIM / BN), dim3(256), 0, stream,
                     att, woT, bo, out);
}